// Round 6
// baseline (80.317 us; speedup 1.0000x reference)
//
#include <hip/hip_runtime.h>
#include <math.h>
#include <float.h>

// Zonotope distance + gradient. One 64-lane wave per point.
// H=48 hyperplanes, V=96 edges.
// R6: H^2 broadcast moved from LDS ds_read to v_readlane (register broadcast,
// no memory latency); edge argmin reduced with a single packed-u64 butterfly
// (exact first-index argmin semantics); payloads fetched via v_readlane.
// ALL floating-point op orders match the numpy reference exactly
// (contract(off); no FMA) — the EPS / argmin boundaries are flip-sensitive.

constexpr int H = 48;
constexpr int V = 96;
constexpr int WPB = 4;          // waves per block
constexpr float ZEPS = 1e-4f;

__device__ __forceinline__ void gload_lds16(const void* g, void* lds) {
  __builtin_amdgcn_global_load_lds(
      (const __attribute__((address_space(1))) void*)g,
      (__attribute__((address_space(3))) void*)lds, 16, 0, 0);
}

__device__ __forceinline__ float readlane_f(float v, int l) {
  return __uint_as_float((unsigned)__builtin_amdgcn_readlane((int)__float_as_uint(v), l));
}

__global__ __launch_bounds__(256, 8) void zono_dist_kernel(
    const float* __restrict__ point,   // [N,3]
    const float* __restrict__ Ag,      // [N,H,3]
    const float* __restrict__ bg,      // [N,H]
    const float* __restrict__ v1g,     // [N,V,3]
    const float* __restrict__ v2g,     // [N,V,3]
    float* __restrict__ out,           // [N] dist ++ [N,3] grad
    int N)
{
#pragma clang fp contract(off)
  __shared__ __align__(16) float sAb[WPB][192];   // A[48*3] ++ b[48]
  // per wave: v1 = floats [0..287], v2 = [288..575], slop = [576..767]
  __shared__ __align__(16) float sEV[WPB][768];

  const int wave = threadIdx.x >> 6;
  const int lane = threadIdx.x & 63;
  const int n = blockIdx.x * WPB + wave;
  if (n >= N) return;
  const int nu = __builtin_amdgcn_readfirstlane(n);   // uniform -> s_load paths

  // ---- async edge payload -> LDS (in flight under the whole H^2 loop) ----
  {
    const float4* V1f4 = (const float4*)(v1g + (size_t)nu * (V * 3)); // 72 f4
    const float4* V2f4 = (const float4*)(v2g + (size_t)nu * (V * 3)); // 72 f4
    const float4* s1 = V1f4 + lane;                                   // f 0..255
    const float4* s2 = (lane < 8) ? (V1f4 + 64 + lane) : (V2f4 + (lane - 8));
    const float4* s3 = (lane < 16) ? (V2f4 + 56 + lane) : (V2f4 + 71); // clamp->slop
    gload_lds16(s1, &sEV[wave][0]);
    gload_lds16(s2, &sEV[wave][256]);
    gload_lds16(s3, &sEV[wave][512]);
  }

  // ---- point via scalar loads (uniform address) ----
  const float px = point[3 * (size_t)nu + 0];
  const float py = point[3 * (size_t)nu + 1];
  const float pz = point[3 * (size_t)nu + 2];

  // ---- coalesced staging: A (36 float4) + b (12 float4) -> LDS ----
  {
    const float4* Af4 = (const float4*)(Ag + (size_t)nu * (H * 3));
    const float4* Bf4 = (const float4*)(bg + (size_t)nu * H);
    float4* dst = (float4*)sAb[wave];
    if (lane < 36)      dst[lane] = Af4[lane];
    else if (lane < 48) dst[lane] = Bf4[lane - 36];
  }

  // ---- own plane from LDS ----
  float ax = 0.f, ay = 0.f, az = 0.f, bb = 1e30f;  // lanes >=H neutral
  if (lane < H) {
    ax = sAb[wave][3 * lane + 0];
    ay = sAb[wave][3 * lane + 1];
    az = sAb[wave][3 * lane + 2];
    bb = sAb[wave][144 + lane];
  }

  // ---- signed facet offset + projection (exact ref op order) ----
  float apb = -INFINITY;
  float qx = 0.f, qy = 0.f, qz = 0.f;
  if (lane < H) {
    apb = ((ax * px + ay * py) + az * pz) - bb;
    qx = px - apb * ax;
    qy = py - apb * ay;
    qz = pz - apb * az;
  }
  const bool is_neg = (bool)__all(apb <= 0.0f);

  // ---- on-zonotope check: q_h broadcast via v_readlane (VALU, no LDS) ----
  // s_{k,h} = ((a_k.x*q_h.x + a_k.y*q_h.y) + a_k.z*q_h.z) - b_k  (ref order)
  unsigned long long bad = 0;           // bit h set => on_zono[h] false
  #pragma unroll
  for (int h = 0; h < H; ++h) {
    float qxh = readlane_f(qx, h);
    float qyh = readlane_f(qy, h);
    float qzh = readlane_f(qz, h);
    float s = ((ax * qxh + ay * qyh) + az * qzh) - bb;
    bad |= (unsigned long long)(!__all(s <= ZEPS)) << h;
  }
  const unsigned long long MASK48 = (1ull << H) - 1;
  const bool any_face = ((~bad) & MASK48) != 0;

  // ---- face distance (gated; rare for random data) ----
  float fv = INFINITY; int fi = 0;
  float fgx = 0.f, fgy = 0.f, fgz = 0.f;
  if (any_face) {
    float pv = INFINITY;
    if (lane < H && !((bad >> lane) & 1)) {
      float dx = px - qx, dy = py - qy, dz = pz - qz;   // ref: p - proj
      pv = sqrtf((dx * dx + dy * dy) + dz * dz);
    }
    fv = pv; fi = lane;
    #pragma unroll
    for (int off = 32; off; off >>= 1) {
      float ov = __shfl_xor(fv, off);
      int oi = __shfl_xor(fi, off);
      if (ov < fv || (ov == fv && oi < fi)) { fv = ov; fi = oi; }
    }
    fgx = __shfl(ax, fi); fgy = __shfl(ay, fi); fgz = __shfl(az, fi);
  }

  // ---- inside-zonotope path (gated; rare) ----
  float nv = 0.f;
  float ngx = 0.f, ngy = 0.f, ngz = 0.f;
  if (is_neg) {
    nv = apb; int ni = lane;
    #pragma unroll
    for (int off = 32; off; off >>= 1) {
      float ov = __shfl_xor(nv, off);
      int oi = __shfl_xor(ni, off);
      if (ov > nv || (ov == nv && oi < ni)) { nv = ov; ni = oi; }
    }
    ngx = __shfl(ax, ni); ngy = __shfl(ay, ni); ngz = __shfl(az, ni);
  }

  // ---- drain async edge loads, then edge distances from LDS ----
  asm volatile("s_waitcnt vmcnt(0)" ::: "memory");
  __builtin_amdgcn_sched_barrier(0);

  float bed, bvx, bvy, bvz;
  int bei;
  const float* ev = sEV[wave];
  {
    int e = lane;                                   // round 1: edges 0..63
    float x1 = ev[3 * e + 0], y1 = ev[3 * e + 1], z1 = ev[3 * e + 2];
    float x2 = ev[288 + 3 * e + 0], y2 = ev[288 + 3 * e + 1], z2 = ev[288 + 3 * e + 2];
    float dx = x2 - x1, dy = y2 - y1, dz = z2 - z1;
    float denom = (dx * dx + dy * dy) + dz * dz;
    float wx = px - x1, wy = py - y1, wz = pz - z1;
    float th = ((wx * dx + wy * dy) + wz * dz) / denom;
    float ts = th < 0.0f ? 0.0f : (th > 1.0f ? 1.0f : th);
    float vx = x1 + ts * dx, vy = y1 + ts * dy, vz = z1 + ts * dz;
    float ex = px - vx, ey = py - vy, ez = pz - vz;
    bed = sqrtf((ex * ex + ey * ey) + ez * ez);
    bei = e; bvx = vx; bvy = vy; bvz = vz;
  }
  {
    int e = 64 | (lane & 31);                       // round 2: duplicated, branch-free
    float x1 = ev[3 * e + 0], y1 = ev[3 * e + 1], z1 = ev[3 * e + 2];
    float x2 = ev[288 + 3 * e + 0], y2 = ev[288 + 3 * e + 1], z2 = ev[288 + 3 * e + 2];
    float dx = x2 - x1, dy = y2 - y1, dz = z2 - z1;
    float denom = (dx * dx + dy * dy) + dz * dz;
    float wx = px - x1, wy = py - y1, wz = pz - z1;
    float th = ((wx * dx + wy * dy) + wz * dz) / denom;
    float ts = th < 0.0f ? 0.0f : (th > 1.0f ? 1.0f : th);
    float vx = x1 + ts * dx, vy = y1 + ts * dy, vz = z1 + ts * dz;
    float ex = px - vx, ey = py - vy, ez = pz - vz;
    float ed = sqrtf((ex * ex + ey * ey) + ez * ez);
    if (ed < bed) { bed = ed; bei = e; bvx = vx; bvy = vy; bvz = vz; }
  }
  // single packed butterfly: key = (ed_bits<<32) | (bei<<6) | lane
  // ed >= 0 so uint bit order == float order; lexicographic min == reference
  // argmin with first-index tiebreak (dup edges carry identical payloads).
  unsigned long long key = ((unsigned long long)__float_as_uint(bed) << 32)
                         | ((unsigned long long)(unsigned)bei << 6)
                         | (unsigned long long)(unsigned)lane;
  #pragma unroll
  for (int off = 32; off; off >>= 1) {
    unsigned long long o = __shfl_xor(key, off);
    if (o < key) key = o;
  }
  const int wl = (int)(key & 63);                  // winner lane (uniform)
  const float m = __uint_as_float((unsigned)(key >> 32));
  const float wvx = readlane_f(bvx, wl);
  const float wvy = readlane_f(bvy, wl);
  const float wvz = readlane_f(bvz, wl);

  // ---- combine; gradient divide vectorized over lanes 0..2 ----
  const bool use_edge = (m < fv);
  float dist;
  float gnum, gden = 1.0f;
  {
    const int d = lane;               // component index for lanes 0..2
    float pd = (d == 0) ? px : (d == 1) ? py : pz;
    float wd = (d == 0) ? wvx : (d == 1) ? wvy : wvz;
    float fd = (d == 0) ? fgx : (d == 1) ? fgy : fgz;
    float nd = (d == 0) ? ngx : (d == 1) ? ngy : ngz;
    if (is_neg) {
      dist = nv; gnum = nd; gden = 1.0f;
    } else if (use_edge) {
      dist = m;  gnum = pd - wd; gden = m;
    } else {
      dist = fv; gnum = fd; gden = 1.0f;
    }
  }
  float g = gnum / gden;              // one v_div sequence for all 3 components
  if (lane < 3) out[(size_t)N + 3 * (size_t)n + lane] = g;
  if (lane == 0) out[n] = dist;
}

extern "C" void kernel_launch(void* const* d_in, const int* in_sizes, int n_in,
                              void* d_out, int out_size, void* d_ws, size_t ws_size,
                              hipStream_t stream) {
  const float* point = (const float*)d_in[0];
  const float* Ag    = (const float*)d_in[1];
  const float* bg    = (const float*)d_in[2];
  const float* v1g   = (const float*)d_in[3];
  const float* v2g   = (const float*)d_in[4];
  float* out = (float*)d_out;

  const int N = in_sizes[0] / 3;
  const int blocks = (N + WPB - 1) / WPB;
  zono_dist_kernel<<<blocks, WPB * 64, 0, stream>>>(point, Ag, bg, v1g, v2g, out, N);
}

// Round 7
// 56.430 us; speedup vs baseline: 1.4233x; 1.4233x over previous
//
#include <hip/hip_runtime.h>
#include <math.h>
#include <float.h>

// Zonotope distance + gradient. One 64-lane wave per point.
// H=48 hyperplanes, V=96 edges.
// R7: no staging LDS at all (A/b and edges read direct from global; edges
// held in registers across the H^2 loop). Edge math packed 2-per-lane
// (lane i owns edges 2i,2i+1 — monotone map). Edge argmin = value-min
// butterfly + ballot + ctz (exact first-index semantics). H^2 loop kept
// verbatim from R5 (LDS q-broadcast + v_pk math).
// ALL floating-point op orders match the numpy reference exactly
// (contract(off); no FMA; sub as add-of-negated which is exact).

typedef float f32x4 __attribute__((ext_vector_type(4)));
typedef float f32x2 __attribute__((ext_vector_type(2)));

constexpr int H = 48;
constexpr int V = 96;
constexpr int WPB = 4;          // waves per block
constexpr float ZEPS = 1e-4f;

__device__ __forceinline__ f32x2 pkmul(f32x2 a, f32x2 b) {
  f32x2 d;
  asm("v_pk_mul_f32 %0, %1, %2" : "=v"(d) : "v"(a), "v"(b));
  return d;
}
__device__ __forceinline__ f32x2 pkadd(f32x2 a, f32x2 b) {
  f32x2 d;
  asm("v_pk_add_f32 %0, %1, %2" : "=v"(d) : "v"(a), "v"(b));
  return d;
}
// a - b, both halves: add with src1 negated (IEEE-exact vs subtraction)
__device__ __forceinline__ f32x2 pksub(f32x2 a, f32x2 b) {
  f32x2 d;
  asm("v_pk_add_f32 %0, %1, %2 neg_lo:[0,1] neg_hi:[0,1]" : "=v"(d) : "v"(a), "v"(b));
  return d;
}

__device__ __forceinline__ float readlane_f(float v, int l) {
  return __uint_as_float((unsigned)__builtin_amdgcn_readlane((int)__float_as_uint(v), l));
}

__global__ __launch_bounds__(256, 8) void zono_dist_kernel(
    const float* __restrict__ point,   // [N,3]
    const float* __restrict__ Ag,      // [N,H,3]
    const float* __restrict__ bg,      // [N,H]
    const float* __restrict__ v1g,     // [N,V,3]
    const float* __restrict__ v2g,     // [N,V,3]
    float* __restrict__ out,           // [N] dist ++ [N,3] grad
    int N)
{
#pragma clang fp contract(off)
  __shared__ __align__(16) float sQx[WPB][48];
  __shared__ __align__(16) float sQy[WPB][48];
  __shared__ __align__(16) float sQz[WPB][48];

  const int wave = threadIdx.x >> 6;
  const int lane = threadIdx.x & 63;
  const int n = blockIdx.x * WPB + wave;
  if (n >= N) return;
  const int nu = __builtin_amdgcn_readfirstlane(n);   // uniform -> s_load paths

  // ---- point via scalar loads (uniform address) ----
  const float px = point[3 * (size_t)nu + 0];
  const float py = point[3 * (size_t)nu + 1];
  const float pz = point[3 * (size_t)nu + 2];

  // ---- own plane direct from global (576B contiguous per wave) ----
  float ax = 0.f, ay = 0.f, az = 0.f, bb = 1e30f;  // lanes >=H neutral
  if (lane < H) {
    const float* ap = Ag + (size_t)nu * (H * 3) + 3 * lane;
    ax = ap[0]; ay = ap[1]; az = ap[2];
    bb = bg[(size_t)nu * H + lane];
  }

  // ---- edge payload direct to registers; lane i owns edges 2i, 2i+1 ----
  // v1 floats [6i..6i+5], v2 same: 3x dwordx2 each, issued early.
  f32x2 e01 = {0.f, 0.f}, e23 = {0.f, 0.f}, e45 = {0.f, 0.f};
  f32x2 f01 = {0.f, 0.f}, f23 = {0.f, 0.f}, f45 = {0.f, 0.f};
  if (lane < 48) {
    const f32x2* p1 = (const f32x2*)(v1g + (size_t)nu * (V * 3)) + 3 * lane;
    const f32x2* p2 = (const f32x2*)(v2g + (size_t)nu * (V * 3)) + 3 * lane;
    e01 = p1[0]; e23 = p1[1]; e45 = p1[2];
    f01 = p2[0]; f23 = p2[1]; f45 = p2[2];
  }

  // ---- signed facet offset + projection (exact ref op order) ----
  float apb = -INFINITY;
  float qx = 0.f, qy = 0.f, qz = 0.f;
  if (lane < H) {
    apb = ((ax * px + ay * py) + az * pz) - bb;
    qx = px - apb * ax;
    qy = py - apb * ay;
    qz = pz - apb * az;
    sQx[wave][lane] = qx;
    sQy[wave][lane] = qy;
    sQz[wave][lane] = qz;
  }
  const bool is_neg = (bool)__all(apb <= 0.0f);

  // ---- on-zonotope check (R5 verbatim): packed fp32, LDS broadcast ----
  const f32x2 ax2 = {ax, ax}, ay2 = {ay, ay}, az2 = {az, az};
  const f32x2 nbb2 = {-bb, -bb};
  unsigned long long bad = 0;           // bit h set => on_zono[h] false
  const f32x4* Qx4 = (const f32x4*)sQx[wave];
  const f32x4* Qy4 = (const f32x4*)sQy[wave];
  const f32x4* Qz4 = (const f32x4*)sQz[wave];
  #pragma unroll
  for (int g = 0; g < 12; ++g) {
    f32x4 X = Qx4[g], Y = Qy4[g], Z = Qz4[g];   // broadcast reads
    f32x2 xlo = __builtin_shufflevector(X, X, 0, 1);
    f32x2 xhi = __builtin_shufflevector(X, X, 2, 3);
    f32x2 ylo = __builtin_shufflevector(Y, Y, 0, 1);
    f32x2 yhi = __builtin_shufflevector(Y, Y, 2, 3);
    f32x2 zlo = __builtin_shufflevector(Z, Z, 0, 1);
    f32x2 zhi = __builtin_shufflevector(Z, Z, 2, 3);
    f32x2 tlo = pkadd(pkmul(ax2, xlo), pkmul(ay2, ylo));
    tlo = pkadd(tlo, pkmul(az2, zlo));
    tlo = pkadd(tlo, nbb2);
    f32x2 thi = pkadd(pkmul(ax2, xhi), pkmul(ay2, yhi));
    thi = pkadd(thi, pkmul(az2, zhi));
    thi = pkadd(thi, nbb2);
    int h = g * 4;
    unsigned long long b0 = (unsigned long long)(!__all(tlo.x <= ZEPS));
    unsigned long long b1 = (unsigned long long)(!__all(tlo.y <= ZEPS));
    unsigned long long b2 = (unsigned long long)(!__all(thi.x <= ZEPS));
    unsigned long long b3 = (unsigned long long)(!__all(thi.y <= ZEPS));
    bad |= (b0 << h) | (b1 << (h + 1)) | (b2 << (h + 2)) | (b3 << (h + 3));
  }
  const unsigned long long MASK48 = (1ull << H) - 1;
  const bool any_face = ((~bad) & MASK48) != 0;

  // ---- face distance (gated; rare for random data) ----
  float fv = INFINITY; int fi = 0;
  float fgx = 0.f, fgy = 0.f, fgz = 0.f;
  if (any_face) {
    float pv = INFINITY;
    if (lane < H && !((bad >> lane) & 1)) {
      float dx = px - qx, dy = py - qy, dz = pz - qz;   // ref: p - proj
      pv = sqrtf((dx * dx + dy * dy) + dz * dz);
    }
    fv = pv; fi = lane;
    #pragma unroll
    for (int off = 32; off; off >>= 1) {
      float ov = __shfl_xor(fv, off);
      int oi = __shfl_xor(fi, off);
      if (ov < fv || (ov == fv && oi < fi)) { fv = ov; fi = oi; }
    }
    fgx = __shfl(ax, fi); fgy = __shfl(ay, fi); fgz = __shfl(az, fi);
  }

  // ---- inside-zonotope path (gated; rare) ----
  float nv = 0.f;
  float ngx = 0.f, ngy = 0.f, ngz = 0.f;
  if (is_neg) {
    nv = apb; int ni = lane;
    #pragma unroll
    for (int off = 32; off; off >>= 1) {
      float ov = __shfl_xor(nv, off);
      int oi = __shfl_xor(ni, off);
      if (ov > nv || (ov == nv && oi < ni)) { nv = ov; ni = oi; }
    }
    ngx = __shfl(ax, ni); ngy = __shfl(ay, ni); ngz = __shfl(az, ni);
  }

  // ---- edge distances: packed, 2 edges per lane (lanes 0..47) ----
  float bed2 = INFINITY;
  float bvx = 0.f, bvy = 0.f, bvz = 0.f;
  {
    const f32x2 Px = {px, px}, Py = {py, py}, Pz = {pz, pz};
    // SoA pairs: component c of edges (2i, 2i+1)
    f32x2 X1 = {e01.x, e23.y}, Y1 = {e01.y, e45.x}, Z1 = {e23.x, e45.y};
    f32x2 X2 = {f01.x, f23.y}, Y2 = {f01.y, f45.x}, Z2 = {f23.x, f45.y};
    f32x2 dx = pksub(X2, X1), dy = pksub(Y2, Y1), dz = pksub(Z2, Z1);
    f32x2 den = pkadd(pkadd(pkmul(dx, dx), pkmul(dy, dy)), pkmul(dz, dz));
    f32x2 wx = pksub(Px, X1), wy = pksub(Py, Y1), wz = pksub(Pz, Z1);
    f32x2 num = pkadd(pkadd(pkmul(wx, dx), pkmul(wy, dy)), pkmul(wz, dz));
    float th0 = num.x / den.x;                 // exact IEEE divs (ref)
    float th1 = num.y / den.y;
    float t0 = th0 < 0.0f ? 0.0f : (th0 > 1.0f ? 1.0f : th0);
    float t1 = th1 < 0.0f ? 0.0f : (th1 > 1.0f ? 1.0f : th1);
    f32x2 tv = {t0, t1};
    f32x2 Vx = pkadd(X1, pkmul(tv, dx));       // ref: v1 + t*d
    f32x2 Vy = pkadd(Y1, pkmul(tv, dy));
    f32x2 Vz = pkadd(Z1, pkmul(tv, dz));
    f32x2 Ex = pksub(Px, Vx), Ey = pksub(Py, Vy), Ez = pksub(Pz, Vz);
    f32x2 ss = pkadd(pkadd(pkmul(Ex, Ex), pkmul(Ey, Ey)), pkmul(Ez, Ez));
    float ed0 = sqrtf(ss.x);
    float ed1 = sqrtf(ss.y);
    if (lane < 48) {
      bool pick = ed1 < ed0;                   // tie -> e0 (lower index)
      bed2 = pick ? ed1 : ed0;
      bvx = pick ? Vx.y : Vx.x;
      bvy = pick ? Vy.y : Vy.x;
      bvz = pick ? Vz.y : Vz.x;
    }
  }
  // value-min butterfly; lane order == index order (monotone map)
  float m = bed2;
  #pragma unroll
  for (int off = 32; off; off >>= 1) {
    float o = __shfl_xor(m, off);
    m = fminf(m, o);
  }
  const unsigned long long cand = __ballot(bed2 == m);
  const int wl = (int)__builtin_ctzll(cand);   // first (lowest-index) winner
  const float wvx = readlane_f(bvx, wl);
  const float wvy = readlane_f(bvy, wl);
  const float wvz = readlane_f(bvz, wl);

  // ---- combine; gradient divide vectorized over lanes 0..2 ----
  const bool use_edge = (m < fv);
  float dist;
  float gnum, gden = 1.0f;
  {
    const int d = lane;               // component index for lanes 0..2
    float pd = (d == 0) ? px : (d == 1) ? py : pz;
    float wd = (d == 0) ? wvx : (d == 1) ? wvy : wvz;
    float fd = (d == 0) ? fgx : (d == 1) ? fgy : fgz;
    float nd = (d == 0) ? ngx : (d == 1) ? ngy : ngz;
    if (is_neg) {
      dist = nv; gnum = nd; gden = 1.0f;
    } else if (use_edge) {
      dist = m;  gnum = pd - wd; gden = m;
    } else {
      dist = fv; gnum = fd; gden = 1.0f;
    }
  }
  float g = gnum / gden;              // one v_div sequence for all 3 components
  if (lane < 3) out[(size_t)N + 3 * (size_t)n + lane] = g;
  if (lane == 0) out[n] = dist;
}

extern "C" void kernel_launch(void* const* d_in, const int* in_sizes, int n_in,
                              void* d_out, int out_size, void* d_ws, size_t ws_size,
                              hipStream_t stream) {
  const float* point = (const float*)d_in[0];
  const float* Ag    = (const float*)d_in[1];
  const float* bg    = (const float*)d_in[2];
  const float* v1g   = (const float*)d_in[3];
  const float* v2g   = (const float*)d_in[4];
  float* out = (float*)d_out;

  const int N = in_sizes[0] / 3;
  const int blocks = (N + WPB - 1) / WPB;
  zono_dist_kernel<<<blocks, WPB * 64, 0, stream>>>(point, Ag, bg, v1g, v2g, out, N);
}

// Round 8
// 46.529 us; speedup vs baseline: 1.7262x; 1.2128x over previous
//
#include <hip/hip_runtime.h>
#include <math.h>
#include <float.h>

// Zonotope distance + gradient.
// R8: 4 points per 64-lane wave (4 groups x 16 lanes). Lane (g,j) owns
// planes 3j..3j+2 and edges 6j..6j+5 of point g. All lanes active in all
// phases. H^2 check: 24 h-pair iterations serve 4 points; per-group q
// broadcast from padded LDS (conflict-free); verdicts via v_max3 + ballot;
// bad-masks accumulated on the scalar pipe. Group reductions: 4-step
// key-packed butterflies with exact first-index tiebreaks.
// ALL floating-point op orders match the numpy reference exactly
// (contract(off); no FMA; packed ops are per-half IEEE identical).

typedef float f32x2 __attribute__((ext_vector_type(2)));
typedef float f4u   __attribute__((ext_vector_type(4), aligned(4)));
typedef unsigned long long u64;
typedef unsigned int u32;

constexpr int H = 48;
constexpr int V = 96;
constexpr int WPB = 4;            // waves per block
constexpr int PPW = 4;            // points per wave
constexpr float ZEPS = 1e-4f;

__device__ __forceinline__ f32x2 pkmul(f32x2 a, f32x2 b) {
  f32x2 d;
  asm("v_pk_mul_f32 %0, %1, %2" : "=v"(d) : "v"(a), "v"(b));
  return d;
}
__device__ __forceinline__ f32x2 pkadd(f32x2 a, f32x2 b) {
  f32x2 d;
  asm("v_pk_add_f32 %0, %1, %2" : "=v"(d) : "v"(a), "v"(b));
  return d;
}
// a - b per half (add of negated src1; IEEE-exact)
__device__ __forceinline__ f32x2 pksub(f32x2 a, f32x2 b) {
  f32x2 d;
  asm("v_pk_add_f32 %0, %1, %2 neg_lo:[0,1] neg_hi:[0,1]" : "=v"(d) : "v"(a), "v"(b));
  return d;
}
__device__ __forceinline__ float max3f(float a, float b, float c) {
  float d;
  asm("v_max3_f32 %0, %1, %2, %3" : "=v"(d) : "v"(a), "v"(b), "v"(c));
  return d;
}

__global__ __launch_bounds__(256, 4) void zono_dist_kernel(
    const float* __restrict__ point,   // [N,3]
    const float* __restrict__ Ag,      // [N,H,3]
    const float* __restrict__ bg,      // [N,H]
    const float* __restrict__ v1g,     // [N,V,3]
    const float* __restrict__ v2g,     // [N,V,3]
    float* __restrict__ out,           // [N] dist ++ [N,3] grad
    int N)
{
#pragma clang fp contract(off)
  // q storage: [wave][comp][group][56]  (48 used; 56-stride => group read
  // windows land 8 banks apart -> conflict-free b64 broadcasts)
  __shared__ __align__(16) float sQ[WPB][3][PPW][56];

  const int wave = threadIdx.x >> 6;
  const int lane = threadIdx.x & 63;
  const int g = lane >> 4;          // group (point within wave)
  const int j = lane & 15;          // lane within group
  int n = blockIdx.x * (WPB * PPW) + wave * PPW + g;
  if (n >= N) n = N - 1;            // duplicate work, duplicate-same writes

  // ---- loads ----
  const float px = point[3 * (size_t)n + 0];
  const float py = point[3 * (size_t)n + 1];
  const float pz = point[3 * (size_t)n + 2];

  const float* ap = Ag + (size_t)n * (H * 3) + 9 * j;   // planes 3j..3j+2
  f4u A0 = *(const f4u*)(ap);        // a0x a0y a0z a1x
  f4u A1 = *(const f4u*)(ap + 4);    // a1y a1z a2x a2y
  const float a2z = ap[8];
  const float* bp = bg + (size_t)n * H + 3 * j;
  const float b0 = bp[0], b1 = bp[1], b2 = bp[2];

  // edges 6j..6j+5: 18 floats per endpoint array, issued early
  const float* e1p = v1g + (size_t)n * (V * 3) + 18 * j;
  const float* e2p = v2g + (size_t)n * (V * 3) + 18 * j;
  f4u Ea = *(const f4u*)(e1p);      f4u Eb = *(const f4u*)(e1p + 4);
  f4u Ec = *(const f4u*)(e1p + 8);  f4u Ed = *(const f4u*)(e1p + 12);
  f32x2 Ee = *(const f32x2*)(e1p + 16);
  f4u Fa = *(const f4u*)(e2p);      f4u Fb = *(const f4u*)(e2p + 4);
  f4u Fc = *(const f4u*)(e2p + 8);  f4u Fd = *(const f4u*)(e2p + 12);
  f32x2 Fe = *(const f32x2*)(e2p + 16);

  const float ax0 = A0.x, ay0 = A0.y, az0 = A0.z;
  const float ax1 = A0.w, ay1 = A1.x, az1 = A1.y;
  const float ax2 = A1.z, ay2 = A1.w, az2 = a2z;

  // ---- signed facet offsets + projections (exact ref op order) ----
  const float apb0 = ((ax0 * px + ay0 * py) + az0 * pz) - b0;
  const float apb1 = ((ax1 * px + ay1 * py) + az1 * pz) - b1;
  const float apb2 = ((ax2 * px + ay2 * py) + az2 * pz) - b2;
  const float q0x = px - apb0 * ax0, q0y = py - apb0 * ay0, q0z = pz - apb0 * az0;
  const float q1x = px - apb1 * ax1, q1y = py - apb1 * ay1, q1z = pz - apb1 * az1;
  const float q2x = px - apb2 * ax2, q2y = py - apb2 * ay2, q2z = pz - apb2 * az2;

  float* qxw = &sQ[wave][0][g][0];
  float* qyw = &sQ[wave][1][g][0];
  float* qzw = &sQ[wave][2][g][0];
  qxw[3 * j + 0] = q0x; qxw[3 * j + 1] = q1x; qxw[3 * j + 2] = q2x;
  qyw[3 * j + 0] = q0y; qyw[3 * j + 1] = q1y; qyw[3 * j + 2] = q2y;
  qzw[3 * j + 0] = q0z; qzw[3 * j + 1] = q1z; qzw[3 * j + 2] = q2z;

  // ---- is_neg per group ----
  const u64 bneg = __ballot(max3f(apb0, apb1, apb2) <= 0.0f);
  u32 negbits = 0;
  if ((bneg & 0x000000000000FFFFull) == 0x000000000000FFFFull) negbits |= 1;
  if ((bneg & 0x00000000FFFF0000ull) == 0x00000000FFFF0000ull) negbits |= 2;
  if ((bneg & 0x0000FFFF00000000ull) == 0x0000FFFF00000000ull) negbits |= 4;
  if ((bneg & 0xFFFF000000000000ull) == 0xFFFF000000000000ull) negbits |= 8;

  // ---- prebuilt broadcast pairs (loop-invariant) ----
  const f32x2 AX0 = {ax0, ax0}, AY0 = {ay0, ay0}, AZ0 = {az0, az0}, B0 = {b0, b0};
  const f32x2 AX1 = {ax1, ax1}, AY1 = {ay1, ay1}, AZ1 = {az1, az1}, B1 = {b1, b1};
  const f32x2 AX2 = {ax2, ax2}, AY2 = {ay2, ay2}, AZ2 = {az2, az2}, B2 = {b2, b2};

  // ---- H^2 check: 24 h-pairs serve all 4 groups at once ----
  u64 bad0 = 0, bad1 = 0, bad2 = 0, bad3 = 0;   // uniform, per group
  const f32x2* qxp = (const f32x2*)qxw;
  const f32x2* qyp = (const f32x2*)qyw;
  const f32x2* qzp = (const f32x2*)qzw;
  #pragma unroll
  for (int hp = 0; hp < 24; ++hp) {
    const f32x2 QX = qxp[hp], QY = qyp[hp], QZ = qzp[hp];  // group broadcasts
    // s = ((ax*qx + ay*qy) + az*qz) - b, two candidates per half
    f32x2 s0 = pksub(pkadd(pkadd(pkmul(AX0, QX), pkmul(AY0, QY)), pkmul(AZ0, QZ)), B0);
    f32x2 s1 = pksub(pkadd(pkadd(pkmul(AX1, QX), pkmul(AY1, QY)), pkmul(AZ1, QZ)), B1);
    f32x2 s2 = pksub(pkadd(pkadd(pkmul(AX2, QX), pkmul(AY2, QY)), pkmul(AZ2, QZ)), B2);
    const u64 bl0 = __ballot(max3f(s0.x, s1.x, s2.x) <= ZEPS);
    const u64 bl1 = __ballot(max3f(s0.y, s1.y, s2.y) <= ZEPS);
    const u64 c0 = 1ull << (2 * hp), c1 = 1ull << (2 * hp + 1);
    bad0 |= ((~bl0 & 0x000000000000FFFFull) ? c0 : 0) | ((~bl1 & 0x000000000000FFFFull) ? c1 : 0);
    bad1 |= ((~bl0 & 0x00000000FFFF0000ull) ? c0 : 0) | ((~bl1 & 0x00000000FFFF0000ull) ? c1 : 0);
    bad2 |= ((~bl0 & 0x0000FFFF00000000ull) ? c0 : 0) | ((~bl1 & 0x0000FFFF00000000ull) ? c1 : 0);
    bad3 |= ((~bl0 & 0xFFFF000000000000ull) ? c0 : 0) | ((~bl1 & 0xFFFF000000000000ull) ? c1 : 0);
  }
  const u64 MASK48 = (1ull << H) - 1;
  const bool anyface = (((~bad0) | (~bad1) | (~bad2) | (~bad3)) & MASK48) != 0;

  // ---- face path (gated; rare) ----
  float fv = INFINITY, fgx = 0.f, fgy = 0.f, fgz = 0.f;
  if (anyface) {
    const u64 badg = (g == 0) ? bad0 : (g == 1) ? bad1 : (g == 2) ? bad2 : bad3;
    const u32 mb = (u32)(badg >> (3 * j));
    float p0 = INFINITY, p1 = INFINITY, p2 = INFINITY;
    if (!(mb & 1)) {
      float dx = px - q0x, dy = py - q0y, dz = pz - q0z;
      p0 = sqrtf((dx * dx + dy * dy) + dz * dz);
    }
    if (!(mb & 2)) {
      float dx = px - q1x, dy = py - q1y, dz = pz - q1z;
      p1 = sqrtf((dx * dx + dy * dy) + dz * dz);
    }
    if (!(mb & 4)) {
      float dx = px - q2x, dy = py - q2y, dz = pz - q2z;
      p2 = sqrtf((dx * dx + dy * dy) + dz * dz);
    }
    float bv = p0; int bk = 0;
    if (p1 < bv) { bv = p1; bk = 1; }
    if (p2 < bv) { bv = p2; bk = 2; }
    u64 key = ((u64)__float_as_uint(bv) << 16) | (u32)(3 * j + bk);
    #pragma unroll
    for (int off = 8; off; off >>= 1) {
      u64 o = __shfl_xor(key, off);
      if (o < key) key = o;
    }
    fv = __uint_as_float((u32)(key >> 16));
    const int ks = (int)(key & 0xFFFF);
    const int owner = 16 * g + ks / 3;
    const int ms = ks - 3 * (ks / 3);
    const float sx0 = __shfl(ax0, owner), sx1 = __shfl(ax1, owner), sx2 = __shfl(ax2, owner);
    const float sy0 = __shfl(ay0, owner), sy1 = __shfl(ay1, owner), sy2 = __shfl(ay2, owner);
    const float sz0 = __shfl(az0, owner), sz1 = __shfl(az1, owner), sz2 = __shfl(az2, owner);
    fgx = (ms == 0) ? sx0 : (ms == 1) ? sx1 : sx2;
    fgy = (ms == 0) ? sy0 : (ms == 1) ? sy1 : sy2;
    fgz = (ms == 0) ? sz0 : (ms == 1) ? sz1 : sz2;
  }

  // ---- inside-zonotope path (gated; rare) ----
  float nv = 0.f, ngx = 0.f, ngy = 0.f, ngz = 0.f;
  if (negbits) {
    float bv = apb0; int bk = 0;                  // strict > keeps first k
    if (apb1 > bv) { bv = apb1; bk = 1; }
    if (apb2 > bv) { bv = apb2; bk = 2; }
    u32 bits = __float_as_uint(bv);
    u32 obits = (bits >> 31) ? ~bits : (bits | 0x80000000u);   // monotone
    u64 key = ((u64)obits << 16) | (u32)(0xFFFF - (3 * j + bk));
    #pragma unroll
    for (int off = 8; off; off >>= 1) {
      u64 o = __shfl_xor(key, off);
      if (o > key) key = o;
    }
    const int ks = (int)(0xFFFF - (key & 0xFFFF));
    const int owner = 16 * g + ks / 3;
    const int ms = ks - 3 * (ks / 3);
    const float v0 = __shfl(apb0, owner), v1 = __shfl(apb1, owner), v2 = __shfl(apb2, owner);
    nv = (ms == 0) ? v0 : (ms == 1) ? v1 : v2;
    const float sx0 = __shfl(ax0, owner), sx1 = __shfl(ax1, owner), sx2 = __shfl(ax2, owner);
    const float sy0 = __shfl(ay0, owner), sy1 = __shfl(ay1, owner), sy2 = __shfl(ay2, owner);
    const float sz0 = __shfl(az0, owner), sz1 = __shfl(az1, owner), sz2 = __shfl(az2, owner);
    ngx = (ms == 0) ? sx0 : (ms == 1) ? sx1 : sx2;
    ngy = (ms == 0) ? sy0 : (ms == 1) ? sy1 : sy2;
    ngz = (ms == 0) ? sz0 : (ms == 1) ? sz1 : sz2;
  }

  // ---- edge distances: 6 edges per lane, exact ref math ----
  const float u[18] = {Ea.x, Ea.y, Ea.z, Ea.w, Eb.x, Eb.y, Eb.z, Eb.w,
                       Ec.x, Ec.y, Ec.z, Ec.w, Ed.x, Ed.y, Ed.z, Ed.w,
                       Ee.x, Ee.y};
  const float w[18] = {Fa.x, Fa.y, Fa.z, Fa.w, Fb.x, Fb.y, Fb.z, Fb.w,
                       Fc.x, Fc.y, Fc.z, Fc.w, Fd.x, Fd.y, Fd.z, Fd.w,
                       Fe.x, Fe.y};
  float bed = INFINITY, bvx = 0.f, bvy = 0.f, bvz = 0.f;
  int bte = 0;
  #pragma unroll
  for (int t = 0; t < 6; ++t) {
    const float x1 = u[3 * t], y1 = u[3 * t + 1], z1 = u[3 * t + 2];
    const float x2 = w[3 * t], y2 = w[3 * t + 1], z2 = w[3 * t + 2];
    const float dx = x2 - x1, dy = y2 - y1, dz = z2 - z1;
    const float den = (dx * dx + dy * dy) + dz * dz;
    const float wx = px - x1, wy = py - y1, wz = pz - z1;
    const float th = ((wx * dx + wy * dy) + wz * dz) / den;
    const float ts = th < 0.0f ? 0.0f : (th > 1.0f ? 1.0f : th);
    const float vx = x1 + ts * dx, vy = y1 + ts * dy, vz = z1 + ts * dz;
    const float ex = px - vx, ey = py - vy, ez = pz - vz;
    const float ed = sqrtf((ex * ex + ey * ey) + ez * ez);
    if (ed < bed) { bed = ed; bte = t; bvx = vx; bvy = vy; bvz = vz; }
  }
  u64 ekey = ((u64)__float_as_uint(bed) << 16) | (u32)(6 * j + bte);
  #pragma unroll
  for (int off = 8; off; off >>= 1) {
    u64 o = __shfl_xor(ekey, off);
    if (o < ekey) ekey = o;
  }
  const float m = __uint_as_float((u32)(ekey >> 16));
  const int el = (int)(ekey & 0xFFFF);
  const int wl = 16 * g + el / 6;
  const float wvx = __shfl(bvx, wl);
  const float wvy = __shfl(bvy, wl);
  const float wvz = __shfl(bvz, wl);

  // ---- combine; lanes j=0..2 write grad comps, j=3 writes dist ----
  const bool isneg = (negbits >> g) & 1;
  const bool use_edge = (m < fv);
  const float pd = (j == 0) ? px : (j == 1) ? py : pz;
  const float wd = (j == 0) ? wvx : (j == 1) ? wvy : wvz;
  const float fd = (j == 0) ? fgx : (j == 1) ? fgy : fgz;
  const float nd = (j == 0) ? ngx : (j == 1) ? ngy : ngz;
  float dist, gnum, gden = 1.0f;
  if (isneg) {
    dist = nv; gnum = nd;
  } else if (use_edge) {
    dist = m; gnum = pd - wd; gden = m;
  } else {
    dist = fv; gnum = fd;
  }
  const float gr = gnum / gden;
  if (j < 3) out[(size_t)N + 3 * (size_t)n + j] = gr;
  if (j == 3) out[n] = dist;
}

extern "C" void kernel_launch(void* const* d_in, const int* in_sizes, int n_in,
                              void* d_out, int out_size, void* d_ws, size_t ws_size,
                              hipStream_t stream) {
  const float* point = (const float*)d_in[0];
  const float* Ag    = (const float*)d_in[1];
  const float* bg    = (const float*)d_in[2];
  const float* v1g   = (const float*)d_in[3];
  const float* v2g   = (const float*)d_in[4];
  float* out = (float*)d_out;

  const int N = in_sizes[0] / 3;
  const int ppb = WPB * PPW;   // 16 points per block
  const int blocks = (N + ppb - 1) / ppb;
  zono_dist_kernel<<<blocks, WPB * 64, 0, stream>>>(point, Ag, bg, v1g, v2g, out, N);
}